// Round 16
// baseline (231.761 us; speedup 1.0000x reference)
//
#include <hip/hip_runtime.h>
#include <hip/hip_bf16.h>
#include <math.h>

#define BB 2
#define C 128
#define L 4096
#define CR4 32
#define RS 4          // row-split factor in k_attn

typedef unsigned short ushort_t;
typedef __attribute__((ext_vector_type(8))) short s16x8;   // 8 bf16 (4 VGPR)
typedef __attribute__((ext_vector_type(4))) float f32x4;

__device__ inline float leaky(float z) { return (z >= 0.f) ? z : 0.2f * z; }

__device__ inline unsigned short f2bf(float f) {
    unsigned int u = __builtin_bit_cast(unsigned int, f);
    unsigned int r = (u + 0x7fffu + ((u >> 16) & 1u)) >> 16;
    return (unsigned short)r;
}
__device__ inline float bf2f(unsigned short b) {
    unsigned int u = ((unsigned int)b) << 16;
    return __builtin_bit_cast(float, u);
}
// single-instruction packed f32->2xbf16 (T12 primitive)
__device__ inline unsigned int cvtpk(float lo, float hi) {
    unsigned int r;
    asm("v_cvt_pk_bf16_f32 %0, %1, %2" : "=v"(r) : "v"(lo), "v"(hi));
    return r;
}

// ---------------------------------------------------------------------------
// Kernel 0a: stacked/composited projection weights in MFMA A-frag order + bias
// Rows: 0..127 value_w | 128..255 query_w | 256..287 lw1w@qw | 288..319 bi1w@qw
// ---------------------------------------------------------------------------
__global__ __launch_bounds__(256) void k_wcomp(
    const float* __restrict__ vw, const float* __restrict__ vb,
    const float* __restrict__ qw, const float* __restrict__ qb,
    const float* __restrict__ lw1w, const float* __restrict__ lw1b,
    const float* __restrict__ bi1w, const float* __restrict__ bi1b,
    ushort_t* __restrict__ WQV, float* __restrict__ biasv)
{
    const int mt = blockIdx.x;            // 0..19
    const int t = threadIdx.x;
    const int kk = t >> 6, lane = t & 63;
    const int row = mt * 16 + (lane & 15);
    const int k0 = kk * 32 + (lane >> 4) * 8;
    s16x8 v;
    if (row < 128) {
        #pragma unroll
        for (int j = 0; j < 8; ++j) v[j] = (short)f2bf(vw[row * 128 + k0 + j]);
    } else if (row < 256) {
        #pragma unroll
        for (int j = 0; j < 8; ++j) v[j] = (short)f2bf(qw[(row - 128) * 128 + k0 + j]);
    } else {
        const float* w1 = (row < 288) ? lw1w + (row - 256) * 128
                                      : bi1w + (row - 288) * 128;
        float acc[8] = {0.f, 0.f, 0.f, 0.f, 0.f, 0.f, 0.f, 0.f};
        #pragma unroll 2
        for (int k = 0; k < 128; ++k) {
            float wv_ = w1[k];
            const float* qr = qw + k * 128 + k0;
            #pragma unroll
            for (int j = 0; j < 8; ++j) acc[j] = fmaf(wv_, qr[j], acc[j]);
        }
        #pragma unroll
        for (int j = 0; j < 8; ++j) v[j] = (short)f2bf(acc[j]);
    }
    *(s16x8*)(WQV + ((size_t)(mt * 4 + kk) * 64 + lane) * 8) = v;

    if (t < 16) {
        int rr = mt * 16 + t;
        float bv;
        if (rr < 128) bv = vb[rr];
        else if (rr < 256) bv = qb[rr - 128];
        else {
            const float* w1 = (rr < 288) ? lw1w + (rr - 256) * 128
                                         : bi1w + (rr - 288) * 128;
            float a = (rr < 288) ? lw1b[rr - 256] : bi1b[rr - 288];
            for (int k = 0; k < 128; ++k) a = fmaf(w1[k], qb[k], a);
            bv = a;
        }
        biasv[rr] = bv;
    }
}

// ---------------------------------------------------------------------------
// Kernel 0b: fused projection GEMM, M-split over blockIdx.y (unchanged R15).
// ---------------------------------------------------------------------------
__global__ __launch_bounds__(256, 1) void k_proj2(
    const float* __restrict__ x, const ushort_t* __restrict__ WQV,
    const float* __restrict__ biasv,
    const float* __restrict__ lw2w, const float* __restrict__ lw2b,
    const float* __restrict__ bi2w, const float* __restrict__ bi2b,
    ushort_t* __restrict__ x2a, ushort_t* __restrict__ x1g,
    float* __restrict__ weiA, float* __restrict__ biiA, float* __restrict__ scA,
    float* __restrict__ cpart)
{
    __shared__ __align__(16) char smem[16384 + 1536];
    char* xT = smem;
    float* biasLDS = (float*)(smem + 16384);   // 320
    float* w2LDS = biasLDS + 320;              // 64: lw2w | bi2w

    const int t = threadIdx.x;
    const int blk = blockIdx.x;
    const int part = blockIdx.y;
    const int b = blk >> 6;
    const int p0 = (blk & 63) * 64;
    const int wv = t >> 6, lane = t & 63, n = lane & 15, g = lane >> 4;

    biasLDS[t] = biasv[t];
    if (t < 64) {
        biasLDS[256 + t] = biasv[256 + t];
        w2LDS[t] = (t < 32) ? lw2w[t] : bi2w[t - 32];
    }

    const int pl = t & 63, cg = t >> 6;
    const float* xb = x + (size_t)b * C * L + p0 + pl;
    #pragma unroll
    for (int i = 0; i < 16; ++i) {
        int c = cg * 32 + i * 2;
        float v0 = xb[(size_t)c * L];
        float v1 = xb[(size_t)(c + 1) * L];
        int slot = c >> 3;
        int offs = (c * 2) & 15;
        int byte = pl * 256 + (((slot ^ (pl & 15)) << 4) | offs);
        *(unsigned int*)(xT + byte) = cvtpk(v0, v1);
    }
    __syncthreads();

    const int brow = wv * 16 + n;
    const int p = p0 + wv * 16 + n;
    const size_t bL = (size_t)b * L;

    if (part == 0) {
        const int mtm[12] = {0, 1, 2, 3, 4, 5, 6, 7, 16, 17, 18, 19};
        f32x4 acc[12];
        #pragma unroll
        for (int i = 0; i < 12; ++i) acc[i] = (f32x4){0.f, 0.f, 0.f, 0.f};
        #pragma unroll
        for (int kk = 0; kk < 4; ++kk) {
            const s16x8 bfr = *(const s16x8*)(xT + brow * 256 + (((4 * kk + g) ^ n) << 4));
            #pragma unroll
            for (int i = 0; i < 12; ++i) {
                const s16x8 afr = *(const s16x8*)(WQV + ((size_t)(mtm[i] * 4 + kk) * 64 + lane) * 8);
                acc[i] = __builtin_amdgcn_mfma_f32_16x16x32_bf16(afr, bfr, acc[i], 0, 0, 0);
            }
        }
        #pragma unroll
        for (int i = 0; i < 12; ++i) {
            const f32x4 bv = *(const f32x4*)(biasLDS + mtm[i] * 16 + g * 4);
            acc[i][0] += bv[0]; acc[i][1] += bv[1];
            acc[i][2] += bv[2]; acc[i][3] += bv[3];
        }
        #pragma unroll
        for (int i = 0; i < 8; ++i)
            #pragma unroll
            for (int r = 0; r < 4; ++r)
                x1g[((size_t)b * C + i * 16 + g * 4 + r) * L + p] = f2bf(acc[i][r]);
        float pw = 0.f, pbb = 0.f;
        #pragma unroll
        for (int i = 8; i < 10; ++i)
            #pragma unroll
            for (int r = 0; r < 4; ++r)
                pw = fmaf(w2LDS[(i - 8) * 16 + g * 4 + r], leaky(acc[i][r]), pw);
        #pragma unroll
        for (int i = 10; i < 12; ++i)
            #pragma unroll
            for (int r = 0; r < 4; ++r)
                pbb = fmaf(w2LDS[32 + (i - 10) * 16 + g * 4 + r], leaky(acc[i][r]), pbb);
        pw += __shfl_xor(pw, 16, 64);  pw += __shfl_xor(pw, 32, 64);
        pbb += __shfl_xor(pbb, 16, 64); pbb += __shfl_xor(pbb, 32, 64);
        if (g == 0) {
            weiA[bL + p] = pw + lw2b[0];
            biiA[bL + p] = pbb + bi2b[0];
        }
    } else {
        f32x4 acc[8];
        #pragma unroll
        for (int i = 0; i < 8; ++i) acc[i] = (f32x4){0.f, 0.f, 0.f, 0.f};
        #pragma unroll
        for (int kk = 0; kk < 4; ++kk) {
            const s16x8 bfr = *(const s16x8*)(xT + brow * 256 + (((4 * kk + g) ^ n) << 4));
            #pragma unroll
            for (int i = 0; i < 8; ++i) {
                const s16x8 afr = *(const s16x8*)(WQV + ((size_t)((8 + i) * 4 + kk) * 64 + lane) * 8);
                acc[i] = __builtin_amdgcn_mfma_f32_16x16x32_bf16(afr, bfr, acc[i], 0, 0, 0);
            }
        }
        #pragma unroll
        for (int i = 0; i < 8; ++i) {
            const f32x4 bv = *(const f32x4*)(biasLDS + (8 + i) * 16 + g * 4);
            acc[i][0] += bv[0]; acc[i][1] += bv[1];
            acc[i][2] += bv[2]; acc[i][3] += bv[3];
        }
        float pn = 0.f;
        #pragma unroll
        for (int i = 0; i < 8; ++i)
            #pragma unroll
            for (int r = 0; r < 4; ++r) pn = fmaf(acc[i][r], acc[i][r], pn);
        pn += __shfl_xor(pn, 16, 64);
        pn += __shfl_xor(pn, 32, 64);
        float scv = fmaxf(sqrtf(pn), 1e-4f);
        float dinv = 1.f / scv;
        if (g == 0) scA[bL + p] = scv;
        #pragma unroll
        for (int i = 0; i < 8; ++i) {
            uint2 uu;
            uu.x = cvtpk(acc[i][0] * dinv, acc[i][1] * dinv);
            uu.y = cvtpk(acc[i][2] * dinv, acc[i][3] * dinv);
            *(uint2*)(x2a + (bL + p) * C + i * 16 + g * 4) = uu;
        }
        float sv[32];
        #pragma unroll
        for (int i = 0; i < 8; ++i)
            #pragma unroll
            for (int r = 0; r < 4; ++r)
                sv[i * 4 + r] = acc[i][r] * dinv;
        #pragma unroll
        for (int mask = 1; mask <= 8; mask <<= 1)
            #pragma unroll
            for (int i = 0; i < 32; ++i)
                sv[i] += __shfl_xor(sv[i], mask, 64);
        __syncthreads();
        float* sumsh = (float*)xT;               // [4][128]
        if (n == 0) {
            #pragma unroll
            for (int i = 0; i < 32; ++i) {
                int ch = (i >> 2) * 16 + g * 4 + (i & 3);
                sumsh[wv * 128 + ch] = sv[i];
            }
        }
        __syncthreads();
        if (t < 128)
            cpart[(size_t)blk * 128 + t] =
                (sumsh[t] + sumsh[128 + t]) + (sumsh[256 + t] + sumsh[384 + t]);
    }
}

// ---------------------------------------------------------------------------
// Kernel 0c: reduce cpart -> cb[b][128] (includes 1/L)
// ---------------------------------------------------------------------------
__global__ __launch_bounds__(128) void k_cb(
    const float* __restrict__ cpart, float* __restrict__ cbv)
{
    const int b = blockIdx.x, t = threadIdx.x;
    float s = 0.f;
    #pragma unroll 4
    for (int j = 0; j < 64; ++j) s += cpart[(size_t)(b * 64 + j) * 128 + t];
    cbv[b * 128 + t] = s * (1.f / (float)L);
}

// ---------------------------------------------------------------------------
// Kernel 3: flash attention v7 — SINGLE-buffered A/X + 2 barriers/tile.
// All A/X LDS reads happen before barrier2 (xf hoist from R15 makes this
// possible); stage(t+1) issues into the same buffers after barrier2 and is
// drained at the end-of-tile barrier (hipcc emits vmcnt(0) lgkmcnt(0) before
// each s_barrier). LDS 40KB -> 4 blocks/CU (16 waves/CU).
// ---------------------------------------------------------------------------
__global__ __launch_bounds__(256, 4) void k_attn(
    const ushort_t* __restrict__ x2a, const ushort_t* __restrict__ x1g,
    const float* __restrict__ scA, const float* __restrict__ weiA,
    const float* __restrict__ biiA, const float* __restrict__ cbv,
    ushort_t* __restrict__ Opb, float* __restrict__ Mp, float* __restrict__ Zp)
{
    __shared__ __align__(16) char smem[40960];
    // Abuf 16KB @0 ; Xbuf 16KB @16384 ; P 4x2KB @32768

    const int t = threadIdx.x;
    const int w = t >> 6, lane = t & 63, n = lane & 15, g = lane >> 4;
    char* Pw = smem + 32768 + w * 2048;

    const int blk = blockIdx.x;               // 512 = B * 64colt * RS
    const int q = blk & (RS - 1);
    const int colt = (blk >> 2) & 63;
    const int b = blk >> 8;
    const int p = colt * 64 + w * 16 + n;
    const size_t bL = (size_t)b * L;

    // Q prologue: unscale x2a -> raw bq; fused dot(cb, raw) for tq
    const s16x8* qrow = (const s16x8*)(x2a + (bL + p) * C);
    const float scp = scA[bL + p];
    s16x8 bq[4];
    float dot = 0.f;
    #pragma unroll
    for (int kk = 0; kk < 4; ++kk) {
        s16x8 raw = qrow[kk * 4 + g];
        const float* cbp = cbv + b * 128 + kk * 32 + g * 8;
        s16x8 u;
        #pragma unroll
        for (int j = 0; j < 8; ++j) {
            float rv = bf2f((unsigned short)raw[j]) * scp;
            u[j] = (short)f2bf(rv);
            dot = fmaf(cbp[j], rv, dot);
        }
        bq[kk] = u;
    }
    dot += __shfl_xor(dot, 16, 64);
    dot += __shfl_xor(dot, 32, 64);
    const float tq = fmaf(weiA[bL + p], dot, -biiA[bL + p]);

    f32x4 Oacc[8];
    #pragma unroll
    for (int ct = 0; ct < 8; ++ct) Oacc[ct] = (f32x4){0.f, 0.f, 0.f, 0.f};
    float Mrun = 0.f, Zrun = 0.f;

    const int l0base = q * (L / RS);
    const char* x2src = (const char*)(x2a + (bL + l0base) * C);
    const char* x1src = (const char*)(x1g + (size_t)b * C * L);

    #define STAGE_X2(buf, tile_)                                                         \
        {   const char* sb = x2src + (size_t)(tile_) * 64 * 256;                          \
            _Pragma("unroll")                                                             \
            for (int rr = 0; rr < 4; ++rr) {                                              \
                int slot = rr * 256 + t;                                                  \
                int lrow = slot >> 4, uu = slot & 15;                                     \
                const char* gp = sb + lrow * 256 + (((uu ^ (lrow & 7))) << 4);            \
                char* lp = (buf) + ((rr * 256 + w * 64) << 4);                            \
                __builtin_amdgcn_global_load_lds(                                         \
                    (const __attribute__((address_space(1))) unsigned int*)gp,            \
                    (__attribute__((address_space(3))) unsigned int*)lp, 16, 0, 0);       \
            } }
    #define STAGE_X1(buf, l0_)                                                            \
        {   _Pragma("unroll")                                                             \
            for (int rr = 0; rr < 4; ++rr) {                                              \
                int slot = rr * 256 + t;                                                  \
                int cr = slot >> 3, uu = slot & 7;                                        \
                const char* gp = x1src + ((size_t)cr * L + (l0_) + ((uu ^ (cr & 7)) << 3)) * 2; \
                char* lp = (buf) + ((rr * 256 + w * 64) << 4);                            \
                __builtin_amdgcn_global_load_lds(                                         \
                    (const __attribute__((address_space(1))) unsigned int*)gp,            \
                    (__attribute__((address_space(3))) unsigned int*)lp, 16, 0, 0);       \
            } }

    char* Abuf = smem;
    char* Xbuf = smem + 16384;

    STAGE_X2(Abuf, 0);
    STAGE_X1(Xbuf, l0base);
    __syncthreads();

    const int swz = n & 7;
    const int NT = L / RS / 64;   // 16

    #pragma unroll 1
    for (int tile = 0; tile < NT; ++tile) {
        // ---- QK: S[64l x 16p] (reads Abuf) ----
        f32x4 s4[4];
        #pragma unroll
        for (int lt = 0; lt < 4; ++lt) s4[lt] = (f32x4){0.f, 0.f, 0.f, 0.f};
        __builtin_amdgcn_s_setprio(1);
        #pragma unroll
        for (int kk = 0; kk < 4; ++kk) {
            #pragma unroll
            for (int lt = 0; lt < 4; ++lt) {
                const s16x8 a = *(const s16x8*)(Abuf + (16 * lt + n) * 256 +
                                                (((4 * kk + g) ^ swz) << 4));
                s4[lt] = __builtin_amdgcn_mfma_f32_16x16x32_bf16(a, bq[kk], s4[lt], 0, 0, 0);
            }
        }
        __builtin_amdgcn_s_setprio(0);

        // ---- X1 fragments to registers (reads Xbuf) ----
        s16x8 xf[16];
        #pragma unroll
        for (int kk2 = 0; kk2 < 2; ++kk2)
            #pragma unroll
            for (int ct = 0; ct < 8; ++ct)
                xf[kk2 * 8 + ct] = *(const s16x8*)(Xbuf + (16 * ct + n) * 128 +
                                                   (((4 * kk2 + g) ^ swz) << 4));

        // all waves done reading A/X buffers (lgkmcnt(0) before s_barrier)
        __syncthreads();

        // ---- stage next tile into the SAME buffers (drained at tile end) ----
        if (tile + 1 < NT) {
            STAGE_X2(Abuf, tile + 1);
            STAGE_X1(Xbuf, l0base + (tile + 1) * 64);
        }

        // ---- gating (branch-free) ----
        float vv[16], sps[16];
        #pragma unroll
        for (int lt = 0; lt < 4; ++lt) {
            #pragma unroll
            for (int r = 0; r < 4; ++r) {
                float s = s4[lt][r];
                float sp = s - tq;
                sps[lt * 4 + r] = sp;
                vv[lt * 4 + r] = s * fmaxf(sp, 0.f);
            }
        }
        float tm[8];
        #pragma unroll
        for (int i = 0; i < 8; ++i) tm[i] = fmaxf(vv[2 * i], vv[2 * i + 1]);
        #pragma unroll
        for (int i = 0; i < 4; ++i) tm[i] = fmaxf(tm[2 * i], tm[2 * i + 1]);
        float tmax = fmaxf(fmaxf(tm[0], tm[1]), fmaxf(tm[2], tm[3]));
        tmax = fmaxf(tmax, __shfl_xor(tmax, 16, 64));
        tmax = fmaxf(tmax, __shfl_xor(tmax, 32, 64));

        if (!__all(tmax <= Mrun + 8.f)) {
            float Mn = fmaxf(Mrun, tmax);
            float so = __expf(Mrun - Mn);
            Mrun = Mn;
            Zrun *= so;
            #pragma unroll
            for (int ct = 0; ct < 8; ++ct) {
                Oacc[ct][0] *= so; Oacc[ct][1] *= so;
                Oacc[ct][2] *= so; Oacc[ct][3] *= so;
            }
        }

        #pragma unroll
        for (int lt = 0; lt < 4; ++lt) {
            float e0 = __expf(vv[lt * 4 + 0] - Mrun);
            float e1 = __expf(vv[lt * 4 + 1] - Mrun);
            float e2 = __expf(vv[lt * 4 + 2] - Mrun);
            float e3 = __expf(vv[lt * 4 + 3] - Mrun);
            Zrun += (e0 + e1) + (e2 + e3);
            float p0 = sps[lt * 4 + 0] > 0.f ? e0 : 0.f;
            float p1 = sps[lt * 4 + 1] > 0.f ? e1 : 0.f;
            float p2 = sps[lt * 4 + 2] > 0.f ? e2 : 0.f;
            float p3 = sps[lt * 4 + 3] > 0.f ? e3 : 0.f;
            int ulog = 2 * lt + (g >> 1);
            int byte = n * 128 + ((ulog ^ swz) << 4) + ((g & 1) << 3);
            uint2 uu;
            uu.x = cvtpk(p0, p1);
            uu.y = cvtpk(p2, p3);
            *(uint2*)(Pw + byte) = uu;
        }

        // ---- PV: O[128c x 16p] += X1^T . P (xf in regs; Pw per-wave private) ----
        __builtin_amdgcn_s_setprio(1);
        #pragma unroll
        for (int kk2 = 0; kk2 < 2; ++kk2) {
            const s16x8 pb = *(const s16x8*)(Pw + n * 128 + (((4 * kk2 + g) ^ swz) << 4));
            #pragma unroll
            for (int ct = 0; ct < 8; ++ct)
                Oacc[ct] = __builtin_amdgcn_mfma_f32_16x16x32_bf16(xf[kk2 * 8 + ct], pb,
                                                                   Oacc[ct], 0, 0, 0);
        }
        __builtin_amdgcn_s_setprio(0);

        // end-of-tile: drains this wave's stage loads (vmcnt0) + publishes
        __syncthreads();
    }
    #undef STAGE_X2
    #undef STAGE_X1

    float z = Zrun;
    z += __shfl_xor(z, 16, 64);
    z += __shfl_xor(z, 32, 64);

    const size_t sset = (size_t)(q * BB + b);
    ushort_t* ob = Opb + (sset * L + p) * C;
    #pragma unroll
    for (int ct = 0; ct < 8; ++ct) {
        uint2 uu;
        uu.x = cvtpk(Oacc[ct][0], Oacc[ct][1]);
        uu.y = cvtpk(Oacc[ct][2], Oacc[ct][3]);
        *(uint2*)(ob + 16 * ct + 4 * g) = uu;
    }
    if (g == 0) {
        Mp[sset * L + p] = Mrun;
        Zp[sset * L + p] = z;
    }
}

// ---------------------------------------------------------------------------
// Kernel 4: fused merge (blocks 0..1023) + conv-weight repack (blocks 1024..1095).
// ---------------------------------------------------------------------------
__global__ __launch_bounds__(256) void k_mergewrep(
    const ushort_t* __restrict__ Opb, const float* __restrict__ Mp,
    const float* __restrict__ Zp, ushort_t* __restrict__ attnb,
    const float* __restrict__ lw, ushort_t* __restrict__ W3)
{
    const int blkid = blockIdx.x;
    const int t = threadIdx.x;
    if (blkid < 1024) {
        const int idx = blkid * 256 + t;
        const int c4 = idx & 31;
        const int p = (idx >> 5) & 4095;
        const int b = idx >> 17;
        size_t is[RS];
        float M = -1e30f;
        float Mq[RS], Zq[RS];
        #pragma unroll
        for (int q = 0; q < RS; ++q) {
            is[q] = (size_t)(q * BB + b) * L + p;
            Mq[q] = Mp[is[q]];
            Zq[q] = Zp[is[q]];
            M = fmaxf(M, Mq[q]);
        }
        float Zt = 0.f;
        float aq[RS];
        #pragma unroll
        for (int q = 0; q < RS; ++q) {
            aq[q] = __expf(Mq[q] - M);
            Zt = fmaf(Zq[q], aq[q], Zt);
        }
        float zi = 1.f / Zt;
        float r0 = 0.f, r1 = 0.f, r2 = 0.f, r3 = 0.f;
        #pragma unroll
        for (int q = 0; q < RS; ++q) {
            float s = aq[q] * zi;
            const ushort4 o = *(const ushort4*)(Opb + is[q] * C + c4 * 4);
            r0 = fmaf(bf2f(o.x), s, r0);
            r1 = fmaf(bf2f(o.y), s, r1);
            r2 = fmaf(bf2f(o.z), s, r2);
            r3 = fmaf(bf2f(o.w), s, r3);
        }
        uint2 uu;
        uu.x = cvtpk(r0, r1);
        uu.y = cvtpk(r2, r3);
        *(uint2*)(attnb + ((size_t)b * L + p) * C + c4 * 4) = uu;
    } else {
        const int tid = (blkid - 1024) * 256 + t;   // 72*256
        const int s = tid >> 9;
        const int r = tid & 511;
        const int mt = r >> 6, lane = r & 63;
        const int co = mt * 16 + (lane & 15), g = lane >> 4;
        const int kk = s >> 2, kc = s & 3;
        const int ci0 = kc * 32 + g * 8;
        s16x8 v;
        #pragma unroll
        for (int j = 0; j < 8; ++j)
            v[j] = (short)f2bf(lw[((size_t)co * 128 + ci0 + j) * 9 + kk]);
        *(s16x8*)(W3 + (size_t)tid * 8) = v;
    }
}

// ---------------------------------------------------------------------------
// Kernel 5: 3x3 conv as implicit GEMM — BARRIER-FREE K-loop (unchanged R15).
// ---------------------------------------------------------------------------
__global__ __launch_bounds__(256, 1) void k_conv(
    const ushort_t* __restrict__ attnb, const float* __restrict__ x,
    const ushort_t* __restrict__ W3, const float* __restrict__ lb,
    float* __restrict__ out)
{
    __shared__ __align__(16) char attnT[49152];   // 192 rows x 256B

    const int t = threadIdx.x;
    const int wv = t >> 6, lane = t & 63, n = lane & 15, g = lane >> 4;
    const int h = blockIdx.x;
    const int half = blockIdx.y;
    const int b = blockIdx.z;

    const char* asrc = (const char*)attnb + ((size_t)b * L + (size_t)(h - 1) * 64) * C * 2;
    #pragma unroll
    for (int rr = 0; rr < 3; ++rr) {
        if ((unsigned)(h - 1 + rr) < 64u) {
            #pragma unroll
            for (int qq = 0; qq < 4; ++qq) {
                int slot = rr * 1024 + qq * 256 + t;
                int lrow = slot >> 4, uu = slot & 15;
                const char* gp = asrc + lrow * 256 + ((uu ^ (lrow & 7)) << 4);
                char* lp = attnT + ((rr * 1024 + qq * 256 + wv * 64) << 4);
                __builtin_amdgcn_global_load_lds(
                    (const __attribute__((address_space(1))) unsigned int*)gp,
                    (__attribute__((address_space(3))) unsigned int*)lp, 16, 0, 0);
            }
        }
    }

    #define WROW(s_, mi_) (*(const s16x8*)(W3 + (((size_t)(s_) * 8 + 2 * wv + (mi_)) * 64 + lane) * 8))

    s16x8 w0a = WROW(0, 0), w0b = WROW(0, 1);
    s16x8 w1a = WROW(1, 0), w1b = WROW(1, 1);

    __syncthreads();   // halo staged

    f32x4 acc[2][2];
    #pragma unroll
    for (int mi = 0; mi < 2; ++mi)
        #pragma unroll
        for (int nt = 0; nt < 2; ++nt) acc[mi][nt] = (f32x4){0.f, 0.f, 0.f, 0.f};

    const s16x8 zer = {0, 0, 0, 0, 0, 0, 0, 0};

    #define CONV_STEP(s_, af0_, af1_)                                                    \
    {   const int kk = (s_) >> 2, kc = (s_) & 3;                                         \
        const int kh = kk / 3, kw = kk - kh * 3;                                         \
        const int dh = kh - 1, dw = kw - 1;                                              \
        const bool hval = ((unsigned)(h + dh) < 64u);                                    \
        _Pragma("unroll")                                                                \
        for (int nt = 0; nt < 2; ++nt) {                                                 \
            int pl = half * 32 + nt * 16 + n;                                            \
            int wd = pl + dw;                                                            \
            bool val = hval && ((unsigned)wd < 64u);                                     \
            int wc = wd < 0 ? 0 : (wd > 63 ? 63 : wd);                                   \
            int lrow = (dh + 1) * 64 + wc;                                               \
            s16x8 bf_ = *(const s16x8*)(attnT + lrow * 256 +                             \
                                        (((kc * 4 + g) ^ (lrow & 7)) << 4));             \
            if (!val) bf_ = zer;                                                         \
            acc[0][nt] = __builtin_amdgcn_mfma_f32_16x16x32_bf16(af0_, bf_, acc[0][nt], 0, 0, 0); \
            acc[1][nt] = __builtin_amdgcn_mfma_f32_16x16x32_bf16(af1_, bf_, acc[1][nt], 0, 0, 0); \
        }                                                                                \
    }

    #pragma unroll 1
    for (int s = 0; s < 36; s += 2) {
        s16x8 af0 = w0a, af1 = w0b;
        if (s + 2 < 36) { w0a = WROW(s + 2, 0); w0b = WROW(s + 2, 1); }
        CONV_STEP(s, af0, af1)
        af0 = w1a; af1 = w1b;
        if (s + 3 < 36) { w1a = WROW(s + 3, 0); w1b = WROW(s + 3, 1); }
        CONV_STEP(s + 1, af0, af1)
    }
    #undef CONV_STEP
    #undef WROW

    const float* xb = x + (size_t)b * C * L + h * 64;
    float* ob = out + (size_t)b * C * L + h * 64;
    #pragma unroll
    for (int mi = 0; mi < 2; ++mi) {
        #pragma unroll
        for (int r = 0; r < 4; ++r) {
            int co = (2 * wv + mi) * 16 + g * 4 + r;
            float bias = lb[co];
            #pragma unroll
            for (int nt = 0; nt < 2; ++nt) {
                int p_ = half * 32 + nt * 16 + n;
                float v = leaky(acc[mi][nt][r] + bias);
                ob[(size_t)co * L + p_] = v + xb[(size_t)co * L + p_];
            }
        }
    }
}

// ---------------------------------------------------------------------------
extern "C" void kernel_launch(void* const* d_in, const int* in_sizes, int n_in,
                              void* d_out, int out_size, void* d_ws, size_t ws_size,
                              hipStream_t stream) {
    const float* x     = (const float*)d_in[0];
    const float* vw    = (const float*)d_in[1];
    const float* vb    = (const float*)d_in[2];
    const float* qw    = (const float*)d_in[3];
    const float* qb    = (const float*)d_in[4];
    const float* lw1w  = (const float*)d_in[5];
    const float* lw1b  = (const float*)d_in[6];
    const float* lw2w  = (const float*)d_in[7];
    const float* lw2b  = (const float*)d_in[8];
    const float* bi1w  = (const float*)d_in[9];
    const float* bi1b  = (const float*)d_in[10];
    const float* bi2w  = (const float*)d_in[11];
    const float* bi2b  = (const float*)d_in[12];
    const float* lw    = (const float*)d_in[13];
    const float* lb    = (const float*)d_in[14];
    float* out = (float*)d_out;

    char* ws = (char*)d_ws;
    ushort_t* x2a  = (ushort_t*)ws;                      // 2 MB  (attnb alias)
    ushort_t* x1g  = (ushort_t*)(ws + 2097152);          // 2 MB  (W3 alias, post-attn)
    ushort_t* Opb  = (ushort_t*)(ws + 4194304);          // 8 MB  (RS=4 partials)
    ushort_t* WQV  = (ushort_t*)(ws + 4194304);          // 80 KB, dead before k_attn
    float* biasv = (float*)(ws + 4194304 + 81920);       // 1280 B, dead before k_attn
    float* weiA  = (float*)(ws + 12582912);              // 32 KB each
    float* biiA  = weiA + BB * L;
    float* scA   = biiA + BB * L;
    float* Mp    = scA + BB * L;                         // RS*BB*L
    float* Zp    = Mp + RS * BB * L;                     // RS*BB*L
    float* cpart = Zp + RS * BB * L;                     // 64 KB
    float* cbv   = cpart + 128 * 128;                    // BB*128
    ushort_t* W3 = x1g;                                  // 288 KB (after k_attn)
    ushort_t* attnb = x2a;

    hipLaunchKernelGGL(k_wcomp, dim3(20), dim3(256), 0, stream,
                       vw, vb, qw, qb, lw1w, lw1b, bi1w, bi1b, WQV, biasv);

    hipLaunchKernelGGL(k_proj2, dim3(128, 2), dim3(256), 0, stream,
                       x, WQV, biasv, lw2w, lw2b, bi2w, bi2b,
                       x2a, x1g, weiA, biiA, scA, cpart);

    hipLaunchKernelGGL(k_cb, dim3(BB), dim3(128), 0, stream, cpart, cbv);

    hipLaunchKernelGGL(k_attn, dim3(BB * 64 * RS), dim3(256), 0, stream,
                       x2a, x1g, scA, weiA, biiA, cbv, Opb, Mp, Zp);

    hipLaunchKernelGGL(k_mergewrep, dim3(1096), dim3(256), 0, stream,
                       Opb, Mp, Zp, attnb, lw, W3);

    hipLaunchKernelGGL(k_conv, dim3(64, 2, BB), dim3(256), 0, stream,
                       attnb, x, W3, lb, out);
}

// Round 17
// 99.364 us; speedup vs baseline: 2.3324x; 2.3324x over previous
//
#include <hip/hip_runtime.h>
#include <hip/hip_bf16.h>
#include <math.h>

#define BB 2
#define C 128
#define L 4096
#define CR4 32
#define RS 4          // row-split factor in k_attn

typedef unsigned short ushort_t;
typedef __attribute__((ext_vector_type(8))) short s16x8;   // 8 bf16 (4 VGPR)
typedef __attribute__((ext_vector_type(4))) float f32x4;

__device__ inline float leaky(float z) { return (z >= 0.f) ? z : 0.2f * z; }

__device__ inline unsigned short f2bf(float f) {
    unsigned int u = __builtin_bit_cast(unsigned int, f);
    unsigned int r = (u + 0x7fffu + ((u >> 16) & 1u)) >> 16;
    return (unsigned short)r;
}
__device__ inline float bf2f(unsigned short b) {
    unsigned int u = ((unsigned int)b) << 16;
    return __builtin_bit_cast(float, u);
}
// single-instruction packed f32->2xbf16 (T12 primitive)
__device__ inline unsigned int cvtpk(float lo, float hi) {
    unsigned int r;
    asm("v_cvt_pk_bf16_f32 %0, %1, %2" : "=v"(r) : "v"(lo), "v"(hi));
    return r;
}

// ---------------------------------------------------------------------------
// Kernel 0a: stacked/composited projection weights in MFMA A-frag order + bias
// Rows: 0..127 value_w | 128..255 query_w | 256..287 lw1w@qw | 288..319 bi1w@qw
// ---------------------------------------------------------------------------
__global__ __launch_bounds__(256) void k_wcomp(
    const float* __restrict__ vw, const float* __restrict__ vb,
    const float* __restrict__ qw, const float* __restrict__ qb,
    const float* __restrict__ lw1w, const float* __restrict__ lw1b,
    const float* __restrict__ bi1w, const float* __restrict__ bi1b,
    ushort_t* __restrict__ WQV, float* __restrict__ biasv)
{
    const int mt = blockIdx.x;            // 0..19
    const int t = threadIdx.x;
    const int kk = t >> 6, lane = t & 63;
    const int row = mt * 16 + (lane & 15);
    const int k0 = kk * 32 + (lane >> 4) * 8;
    s16x8 v;
    if (row < 128) {
        #pragma unroll
        for (int j = 0; j < 8; ++j) v[j] = (short)f2bf(vw[row * 128 + k0 + j]);
    } else if (row < 256) {
        #pragma unroll
        for (int j = 0; j < 8; ++j) v[j] = (short)f2bf(qw[(row - 128) * 128 + k0 + j]);
    } else {
        const float* w1 = (row < 288) ? lw1w + (row - 256) * 128
                                      : bi1w + (row - 288) * 128;
        float acc[8] = {0.f, 0.f, 0.f, 0.f, 0.f, 0.f, 0.f, 0.f};
        #pragma unroll 2
        for (int k = 0; k < 128; ++k) {
            float wv_ = w1[k];
            const float* qr = qw + k * 128 + k0;
            #pragma unroll
            for (int j = 0; j < 8; ++j) acc[j] = fmaf(wv_, qr[j], acc[j]);
        }
        #pragma unroll
        for (int j = 0; j < 8; ++j) v[j] = (short)f2bf(acc[j]);
    }
    *(s16x8*)(WQV + ((size_t)(mt * 4 + kk) * 64 + lane) * 8) = v;

    if (t < 16) {
        int rr = mt * 16 + t;
        float bv;
        if (rr < 128) bv = vb[rr];
        else if (rr < 256) bv = qb[rr - 128];
        else {
            const float* w1 = (rr < 288) ? lw1w + (rr - 256) * 128
                                         : bi1w + (rr - 288) * 128;
            float a = (rr < 288) ? lw1b[rr - 256] : bi1b[rr - 288];
            for (int k = 0; k < 128; ++k) a = fmaf(w1[k], qb[k], a);
            bv = a;
        }
        biasv[rr] = bv;
    }
}

// ---------------------------------------------------------------------------
// Kernel 0b: fused projection GEMM, M-split over blockIdx.y.
// ---------------------------------------------------------------------------
__global__ __launch_bounds__(256, 1) void k_proj2(
    const float* __restrict__ x, const ushort_t* __restrict__ WQV,
    const float* __restrict__ biasv,
    const float* __restrict__ lw2w, const float* __restrict__ lw2b,
    const float* __restrict__ bi2w, const float* __restrict__ bi2b,
    ushort_t* __restrict__ x2a, ushort_t* __restrict__ x1g,
    float* __restrict__ weiA, float* __restrict__ biiA, float* __restrict__ scA,
    float* __restrict__ cpart)
{
    __shared__ __align__(16) char smem[16384 + 1536];
    char* xT = smem;
    float* biasLDS = (float*)(smem + 16384);   // 320
    float* w2LDS = biasLDS + 320;              // 64: lw2w | bi2w

    const int t = threadIdx.x;
    const int blk = blockIdx.x;
    const int part = blockIdx.y;
    const int b = blk >> 6;
    const int p0 = (blk & 63) * 64;
    const int wv = t >> 6, lane = t & 63, n = lane & 15, g = lane >> 4;

    biasLDS[t] = biasv[t];
    if (t < 64) {
        biasLDS[256 + t] = biasv[256 + t];
        w2LDS[t] = (t < 32) ? lw2w[t] : bi2w[t - 32];
    }

    const int pl = t & 63, cg = t >> 6;
    const float* xb = x + (size_t)b * C * L + p0 + pl;
    #pragma unroll
    for (int i = 0; i < 16; ++i) {
        int c = cg * 32 + i * 2;
        float v0 = xb[(size_t)c * L];
        float v1 = xb[(size_t)(c + 1) * L];
        int slot = c >> 3;
        int offs = (c * 2) & 15;
        int byte = pl * 256 + (((slot ^ (pl & 15)) << 4) | offs);
        *(unsigned int*)(xT + byte) = cvtpk(v0, v1);
    }
    __syncthreads();

    const int brow = wv * 16 + n;
    const int p = p0 + wv * 16 + n;
    const size_t bL = (size_t)b * L;

    if (part == 0) {
        const int mtm[12] = {0, 1, 2, 3, 4, 5, 6, 7, 16, 17, 18, 19};
        f32x4 acc[12];
        #pragma unroll
        for (int i = 0; i < 12; ++i) acc[i] = (f32x4){0.f, 0.f, 0.f, 0.f};
        #pragma unroll
        for (int kk = 0; kk < 4; ++kk) {
            const s16x8 bfr = *(const s16x8*)(xT + brow * 256 + (((4 * kk + g) ^ n) << 4));
            #pragma unroll
            for (int i = 0; i < 12; ++i) {
                const s16x8 afr = *(const s16x8*)(WQV + ((size_t)(mtm[i] * 4 + kk) * 64 + lane) * 8);
                acc[i] = __builtin_amdgcn_mfma_f32_16x16x32_bf16(afr, bfr, acc[i], 0, 0, 0);
            }
        }
        #pragma unroll
        for (int i = 0; i < 12; ++i) {
            const f32x4 bv = *(const f32x4*)(biasLDS + mtm[i] * 16 + g * 4);
            acc[i][0] += bv[0]; acc[i][1] += bv[1];
            acc[i][2] += bv[2]; acc[i][3] += bv[3];
        }
        #pragma unroll
        for (int i = 0; i < 8; ++i)
            #pragma unroll
            for (int r = 0; r < 4; ++r)
                x1g[((size_t)b * C + i * 16 + g * 4 + r) * L + p] = f2bf(acc[i][r]);
        float pw = 0.f, pbb = 0.f;
        #pragma unroll
        for (int i = 8; i < 10; ++i)
            #pragma unroll
            for (int r = 0; r < 4; ++r)
                pw = fmaf(w2LDS[(i - 8) * 16 + g * 4 + r], leaky(acc[i][r]), pw);
        #pragma unroll
        for (int i = 10; i < 12; ++i)
            #pragma unroll
            for (int r = 0; r < 4; ++r)
                pbb = fmaf(w2LDS[32 + (i - 10) * 16 + g * 4 + r], leaky(acc[i][r]), pbb);
        pw += __shfl_xor(pw, 16, 64);  pw += __shfl_xor(pw, 32, 64);
        pbb += __shfl_xor(pbb, 16, 64); pbb += __shfl_xor(pbb, 32, 64);
        if (g == 0) {
            weiA[bL + p] = pw + lw2b[0];
            biiA[bL + p] = pbb + bi2b[0];
        }
    } else {
        f32x4 acc[8];
        #pragma unroll
        for (int i = 0; i < 8; ++i) acc[i] = (f32x4){0.f, 0.f, 0.f, 0.f};
        #pragma unroll
        for (int kk = 0; kk < 4; ++kk) {
            const s16x8 bfr = *(const s16x8*)(xT + brow * 256 + (((4 * kk + g) ^ n) << 4));
            #pragma unroll
            for (int i = 0; i < 8; ++i) {
                const s16x8 afr = *(const s16x8*)(WQV + ((size_t)((8 + i) * 4 + kk) * 64 + lane) * 8);
                acc[i] = __builtin_amdgcn_mfma_f32_16x16x32_bf16(afr, bfr, acc[i], 0, 0, 0);
            }
        }
        #pragma unroll
        for (int i = 0; i < 8; ++i) {
            const f32x4 bv = *(const f32x4*)(biasLDS + (8 + i) * 16 + g * 4);
            acc[i][0] += bv[0]; acc[i][1] += bv[1];
            acc[i][2] += bv[2]; acc[i][3] += bv[3];
        }
        float pn = 0.f;
        #pragma unroll
        for (int i = 0; i < 8; ++i)
            #pragma unroll
            for (int r = 0; r < 4; ++r) pn = fmaf(acc[i][r], acc[i][r], pn);
        pn += __shfl_xor(pn, 16, 64);
        pn += __shfl_xor(pn, 32, 64);
        float scv = fmaxf(sqrtf(pn), 1e-4f);
        float dinv = 1.f / scv;
        if (g == 0) scA[bL + p] = scv;
        #pragma unroll
        for (int i = 0; i < 8; ++i) {
            uint2 uu;
            uu.x = cvtpk(acc[i][0] * dinv, acc[i][1] * dinv);
            uu.y = cvtpk(acc[i][2] * dinv, acc[i][3] * dinv);
            *(uint2*)(x2a + (bL + p) * C + i * 16 + g * 4) = uu;
        }
        float sv[32];
        #pragma unroll
        for (int i = 0; i < 8; ++i)
            #pragma unroll
            for (int r = 0; r < 4; ++r)
                sv[i * 4 + r] = acc[i][r] * dinv;
        #pragma unroll
        for (int mask = 1; mask <= 8; mask <<= 1)
            #pragma unroll
            for (int i = 0; i < 32; ++i)
                sv[i] += __shfl_xor(sv[i], mask, 64);
        __syncthreads();
        float* sumsh = (float*)xT;               // [4][128]
        if (n == 0) {
            #pragma unroll
            for (int i = 0; i < 32; ++i) {
                int ch = (i >> 2) * 16 + g * 4 + (i & 3);
                sumsh[wv * 128 + ch] = sv[i];
            }
        }
        __syncthreads();
        if (t < 128)
            cpart[(size_t)blk * 128 + t] =
                (sumsh[t] + sumsh[128 + t]) + (sumsh[256 + t] + sumsh[384 + t]);
    }
}

// ---------------------------------------------------------------------------
// Kernel 0c: reduce cpart -> cb[b][128] (includes 1/L)
// ---------------------------------------------------------------------------
__global__ __launch_bounds__(128) void k_cb(
    const float* __restrict__ cpart, float* __restrict__ cbv)
{
    const int b = blockIdx.x, t = threadIdx.x;
    float s = 0.f;
    #pragma unroll 4
    for (int j = 0; j < 64; ++j) s += cpart[(size_t)(b * 64 + j) * 128 + t];
    cbv[b * 128 + t] = s * (1.f / (float)L);
}

// ---------------------------------------------------------------------------
// Kernel 3: flash attention — R13/R15 proven best (41.4 us).
// Grid 512; 4 waves, 1 col-tile/wave; dbuf 72KB LDS -> 2 blocks/CU;
// conflict-free 256B/128B-row XOR-8 layouts; setprio; inline tq; defer-max.
// ---------------------------------------------------------------------------
__global__ __launch_bounds__(256, 2) void k_attn(
    const ushort_t* __restrict__ x2a, const ushort_t* __restrict__ x1g,
    const float* __restrict__ scA, const float* __restrict__ weiA,
    const float* __restrict__ biiA, const float* __restrict__ cbv,
    ushort_t* __restrict__ Opb, float* __restrict__ Mp, float* __restrict__ Zp)
{
    __shared__ __align__(16) char smem[73728];
    // Abuf 2x16KB @0/16384 ; Xbuf 2x16KB @32768/49152 ; P 4x2KB @65536

    const int t = threadIdx.x;
    const int w = t >> 6, lane = t & 63, n = lane & 15, g = lane >> 4;
    char* Pw = smem + 65536 + w * 2048;

    const int blk = blockIdx.x;               // 512 = B * 64colt * RS
    const int q = blk & (RS - 1);
    const int colt = (blk >> 2) & 63;
    const int b = blk >> 8;
    const int p = colt * 64 + w * 16 + n;
    const size_t bL = (size_t)b * L;

    // Q prologue: unscale x2a -> raw bq; fused dot(cb, raw) for tq
    const s16x8* qrow = (const s16x8*)(x2a + (bL + p) * C);
    const float scp = scA[bL + p];
    s16x8 bq[4];
    float dot = 0.f;
    #pragma unroll
    for (int kk = 0; kk < 4; ++kk) {
        s16x8 raw = qrow[kk * 4 + g];
        const float* cbp = cbv + b * 128 + kk * 32 + g * 8;
        s16x8 u;
        #pragma unroll
        for (int j = 0; j < 8; ++j) {
            float rv = bf2f((unsigned short)raw[j]) * scp;
            u[j] = (short)f2bf(rv);
            dot = fmaf(cbp[j], rv, dot);
        }
        bq[kk] = u;
    }
    dot += __shfl_xor(dot, 16, 64);
    dot += __shfl_xor(dot, 32, 64);
    const float tq = fmaf(weiA[bL + p], dot, -biiA[bL + p]);

    f32x4 Oacc[8];
    #pragma unroll
    for (int ct = 0; ct < 8; ++ct) Oacc[ct] = (f32x4){0.f, 0.f, 0.f, 0.f};
    float Mrun = 0.f, Zrun = 0.f;

    const int l0base = q * (L / RS);
    const char* x2src = (const char*)(x2a + (bL + l0base) * C);
    const char* x1src = (const char*)(x1g + (size_t)b * C * L);

    #define STAGE_X2(buf, tile_)                                                         \
        {   const char* sb = x2src + (size_t)(tile_) * 64 * 256;                          \
            _Pragma("unroll")                                                             \
            for (int rr = 0; rr < 4; ++rr) {                                              \
                int slot = rr * 256 + t;                                                  \
                int lrow = slot >> 4, uu = slot & 15;                                     \
                const char* gp = sb + lrow * 256 + (((uu ^ (lrow & 7))) << 4);            \
                char* lp = (buf) + ((rr * 256 + w * 64) << 4);                            \
                __builtin_amdgcn_global_load_lds(                                         \
                    (const __attribute__((address_space(1))) unsigned int*)gp,            \
                    (__attribute__((address_space(3))) unsigned int*)lp, 16, 0, 0);       \
            } }
    #define STAGE_X1(buf, l0_)                                                            \
        {   _Pragma("unroll")                                                             \
            for (int rr = 0; rr < 4; ++rr) {                                              \
                int slot = rr * 256 + t;                                                  \
                int cr = slot >> 3, uu = slot & 7;                                        \
                const char* gp = x1src + ((size_t)cr * L + (l0_) + ((uu ^ (cr & 7)) << 3)) * 2; \
                char* lp = (buf) + ((rr * 256 + w * 64) << 4);                            \
                __builtin_amdgcn_global_load_lds(                                         \
                    (const __attribute__((address_space(1))) unsigned int*)gp,            \
                    (__attribute__((address_space(3))) unsigned int*)lp, 16, 0, 0);       \
            } }

    char* Abuf0 = smem;          char* Abuf1 = smem + 16384;
    char* Xbuf0 = smem + 32768;  char* Xbuf1 = smem + 49152;

    STAGE_X2(Abuf0, 0);
    STAGE_X1(Xbuf0, l0base);
    __syncthreads();

    const int swz = n & 7;
    const int NT = L / RS / 64;   // 16

    #pragma unroll 1
    for (int tile = 0; tile < NT; ++tile) {
        char* Ab = (tile & 1) ? Abuf1 : Abuf0;
        char* Xb = (tile & 1) ? Xbuf1 : Xbuf0;
        if (tile + 1 < NT) {
            char* An = (tile & 1) ? Abuf0 : Abuf1;
            char* Xn = (tile & 1) ? Xbuf0 : Xbuf1;
            STAGE_X2(An, tile + 1);
            STAGE_X1(Xn, l0base + (tile + 1) * 64);
        }

        // ---- QK: S[64l x 16p] ----
        f32x4 s4[4];
        #pragma unroll
        for (int lt = 0; lt < 4; ++lt) s4[lt] = (f32x4){0.f, 0.f, 0.f, 0.f};
        __builtin_amdgcn_s_setprio(1);
        #pragma unroll
        for (int kk = 0; kk < 4; ++kk) {
            #pragma unroll
            for (int lt = 0; lt < 4; ++lt) {
                const s16x8 a = *(const s16x8*)(Ab + (16 * lt + n) * 256 +
                                                (((4 * kk + g) ^ swz) << 4));
                s4[lt] = __builtin_amdgcn_mfma_f32_16x16x32_bf16(a, bq[kk], s4[lt], 0, 0, 0);
            }
        }
        __builtin_amdgcn_s_setprio(0);

        // ---- gating (branch-free) ----
        float vv[16], sps[16];
        #pragma unroll
        for (int lt = 0; lt < 4; ++lt) {
            #pragma unroll
            for (int r = 0; r < 4; ++r) {
                float s = s4[lt][r];
                float sp = s - tq;
                sps[lt * 4 + r] = sp;
                vv[lt * 4 + r] = s * fmaxf(sp, 0.f);
            }
        }
        float tm[8];
        #pragma unroll
        for (int i = 0; i < 8; ++i) tm[i] = fmaxf(vv[2 * i], vv[2 * i + 1]);
        #pragma unroll
        for (int i = 0; i < 4; ++i) tm[i] = fmaxf(tm[2 * i], tm[2 * i + 1]);
        float tmax = fmaxf(fmaxf(tm[0], tm[1]), fmaxf(tm[2], tm[3]));
        tmax = fmaxf(tmax, __shfl_xor(tmax, 16, 64));
        tmax = fmaxf(tmax, __shfl_xor(tmax, 32, 64));

        if (!__all(tmax <= Mrun + 8.f)) {
            float Mn = fmaxf(Mrun, tmax);
            float so = __expf(Mrun - Mn);
            Mrun = Mn;
            Zrun *= so;
            #pragma unroll
            for (int ct = 0; ct < 8; ++ct) {
                Oacc[ct][0] *= so; Oacc[ct][1] *= so;
                Oacc[ct][2] *= so; Oacc[ct][3] *= so;
            }
        }

        #pragma unroll
        for (int lt = 0; lt < 4; ++lt) {
            float e0 = __expf(vv[lt * 4 + 0] - Mrun);
            float e1 = __expf(vv[lt * 4 + 1] - Mrun);
            float e2 = __expf(vv[lt * 4 + 2] - Mrun);
            float e3 = __expf(vv[lt * 4 + 3] - Mrun);
            Zrun += (e0 + e1) + (e2 + e3);
            float p0 = sps[lt * 4 + 0] > 0.f ? e0 : 0.f;
            float p1 = sps[lt * 4 + 1] > 0.f ? e1 : 0.f;
            float p2 = sps[lt * 4 + 2] > 0.f ? e2 : 0.f;
            float p3 = sps[lt * 4 + 3] > 0.f ? e3 : 0.f;
            int ulog = 2 * lt + (g >> 1);
            int byte = n * 128 + ((ulog ^ swz) << 4) + ((g & 1) << 3);
            uint2 uu;
            uu.x = cvtpk(p0, p1);
            uu.y = cvtpk(p2, p3);
            *(uint2*)(Pw + byte) = uu;
        }

        // ---- PV: O[128c x 16p] += X1^T . P ----
        __builtin_amdgcn_s_setprio(1);
        #pragma unroll
        for (int kk2 = 0; kk2 < 2; ++kk2) {
            const s16x8 pb = *(const s16x8*)(Pw + n * 128 + (((4 * kk2 + g) ^ swz) << 4));
            #pragma unroll
            for (int ct = 0; ct < 8; ++ct) {
                const s16x8 a = *(const s16x8*)(Xb + (16 * ct + n) * 128 +
                                                (((4 * kk2 + g) ^ swz) << 4));
                Oacc[ct] = __builtin_amdgcn_mfma_f32_16x16x32_bf16(a, pb, Oacc[ct], 0, 0, 0);
            }
        }
        __builtin_amdgcn_s_setprio(0);
        __syncthreads();
    }
    #undef STAGE_X2
    #undef STAGE_X1

    float z = Zrun;
    z += __shfl_xor(z, 16, 64);
    z += __shfl_xor(z, 32, 64);

    const size_t sset = (size_t)(q * BB + b);
    ushort_t* ob = Opb + (sset * L + p) * C;
    #pragma unroll
    for (int ct = 0; ct < 8; ++ct) {
        uint2 uu;
        uu.x = cvtpk(Oacc[ct][0], Oacc[ct][1]);
        uu.y = cvtpk(Oacc[ct][2], Oacc[ct][3]);
        *(uint2*)(ob + 16 * ct + 4 * g) = uu;
    }
    if (g == 0) {
        Mp[sset * L + p] = Mrun;
        Zp[sset * L + p] = z;
    }
}

// ---------------------------------------------------------------------------
// Kernel 4: fused merge (blocks 0..1023) + conv-weight repack (blocks 1024..1095).
// ---------------------------------------------------------------------------
__global__ __launch_bounds__(256) void k_mergewrep(
    const ushort_t* __restrict__ Opb, const float* __restrict__ Mp,
    const float* __restrict__ Zp, ushort_t* __restrict__ attnb,
    const float* __restrict__ lw, ushort_t* __restrict__ W3)
{
    const int blkid = blockIdx.x;
    const int t = threadIdx.x;
    if (blkid < 1024) {
        const int idx = blkid * 256 + t;
        const int c4 = idx & 31;
        const int p = (idx >> 5) & 4095;
        const int b = idx >> 17;
        size_t is[RS];
        float M = -1e30f;
        float Mq[RS], Zq[RS];
        #pragma unroll
        for (int q = 0; q < RS; ++q) {
            is[q] = (size_t)(q * BB + b) * L + p;
            Mq[q] = Mp[is[q]];
            Zq[q] = Zp[is[q]];
            M = fmaxf(M, Mq[q]);
        }
        float Zt = 0.f;
        float aq[RS];
        #pragma unroll
        for (int q = 0; q < RS; ++q) {
            aq[q] = __expf(Mq[q] - M);
            Zt = fmaf(Zq[q], aq[q], Zt);
        }
        float zi = 1.f / Zt;
        float r0 = 0.f, r1 = 0.f, r2 = 0.f, r3 = 0.f;
        #pragma unroll
        for (int q = 0; q < RS; ++q) {
            float s = aq[q] * zi;
            const ushort4 o = *(const ushort4*)(Opb + is[q] * C + c4 * 4);
            r0 = fmaf(bf2f(o.x), s, r0);
            r1 = fmaf(bf2f(o.y), s, r1);
            r2 = fmaf(bf2f(o.z), s, r2);
            r3 = fmaf(bf2f(o.w), s, r3);
        }
        uint2 uu;
        uu.x = cvtpk(r0, r1);
        uu.y = cvtpk(r2, r3);
        *(uint2*)(attnb + ((size_t)b * L + p) * C + c4 * 4) = uu;
    } else {
        const int tid = (blkid - 1024) * 256 + t;   // 72*256
        const int s = tid >> 9;
        const int r = tid & 511;
        const int mt = r >> 6, lane = r & 63;
        const int co = mt * 16 + (lane & 15), g = lane >> 4;
        const int kk = s >> 2, kc = s & 3;
        const int ci0 = kc * 32 + g * 8;
        s16x8 v;
        #pragma unroll
        for (int j = 0; j < 8; ++j)
            v[j] = (short)f2bf(lw[((size_t)co * 128 + ci0 + j) * 9 + kk]);
        *(s16x8*)(W3 + (size_t)tid * 8) = v;
    }
}

// ---------------------------------------------------------------------------
// Kernel 5: 3x3 conv as implicit GEMM — BARRIER-FREE K-loop.
// ---------------------------------------------------------------------------
__global__ __launch_bounds__(256, 1) void k_conv(
    const ushort_t* __restrict__ attnb, const float* __restrict__ x,
    const ushort_t* __restrict__ W3, const float* __restrict__ lb,
    float* __restrict__ out)
{
    __shared__ __align__(16) char attnT[49152];   // 192 rows x 256B

    const int t = threadIdx.x;
    const int wv = t >> 6, lane = t & 63, n = lane & 15, g = lane >> 4;
    const int h = blockIdx.x;
    const int half = blockIdx.y;
    const int b = blockIdx.z;

    const char* asrc = (const char*)attnb + ((size_t)b * L + (size_t)(h - 1) * 64) * C * 2;
    #pragma unroll
    for (int rr = 0; rr < 3; ++rr) {
        if ((unsigned)(h - 1 + rr) < 64u) {
            #pragma unroll
            for (int qq = 0; qq < 4; ++qq) {
                int slot = rr * 1024 + qq * 256 + t;
                int lrow = slot >> 4, uu = slot & 15;
                const char* gp = asrc + lrow * 256 + ((uu ^ (lrow & 7)) << 4);
                char* lp = attnT + ((rr * 1024 + qq * 256 + wv * 64) << 4);
                __builtin_amdgcn_global_load_lds(
                    (const __attribute__((address_space(1))) unsigned int*)gp,
                    (__attribute__((address_space(3))) unsigned int*)lp, 16, 0, 0);
            }
        }
    }

    #define WROW(s_, mi_) (*(const s16x8*)(W3 + (((size_t)(s_) * 8 + 2 * wv + (mi_)) * 64 + lane) * 8))

    s16x8 w0a = WROW(0, 0), w0b = WROW(0, 1);
    s16x8 w1a = WROW(1, 0), w1b = WROW(1, 1);

    __syncthreads();   // halo staged

    f32x4 acc[2][2];
    #pragma unroll
    for (int mi = 0; mi < 2; ++mi)
        #pragma unroll
        for (int nt = 0; nt < 2; ++nt) acc[mi][nt] = (f32x4){0.f, 0.f, 0.f, 0.f};

    const s16x8 zer = {0, 0, 0, 0, 0, 0, 0, 0};

    #define CONV_STEP(s_, af0_, af1_)                                                    \
    {   const int kk = (s_) >> 2, kc = (s_) & 3;                                         \
        const int kh = kk / 3, kw = kk - kh * 3;                                         \
        const int dh = kh - 1, dw = kw - 1;                                              \
        const bool hval = ((unsigned)(h + dh) < 64u);                                    \
        _Pragma("unroll")                                                                \
        for (int nt = 0; nt < 2; ++nt) {                                                 \
            int pl = half * 32 + nt * 16 + n;                                            \
            int wd = pl + dw;                                                            \
            bool val = hval && ((unsigned)wd < 64u);                                     \
            int wc = wd < 0 ? 0 : (wd > 63 ? 63 : wd);                                   \
            int lrow = (dh + 1) * 64 + wc;                                               \
            s16x8 bf_ = *(const s16x8*)(attnT + lrow * 256 +                             \
                                        (((kc * 4 + g) ^ (lrow & 7)) << 4));             \
            if (!val) bf_ = zer;                                                         \
            acc[0][nt] = __builtin_amdgcn_mfma_f32_16x16x32_bf16(af0_, bf_, acc[0][nt], 0, 0, 0); \
            acc[1][nt] = __builtin_amdgcn_mfma_f32_16x16x32_bf16(af1_, bf_, acc[1][nt], 0, 0, 0); \
        }                                                                                \
    }

    #pragma unroll 1
    for (int s = 0; s < 36; s += 2) {
        s16x8 af0 = w0a, af1 = w0b;
        if (s + 2 < 36) { w0a = WROW(s + 2, 0); w0b = WROW(s + 2, 1); }
        CONV_STEP(s, af0, af1)
        af0 = w1a; af1 = w1b;
        if (s + 3 < 36) { w1a = WROW(s + 3, 0); w1b = WROW(s + 3, 1); }
        CONV_STEP(s + 1, af0, af1)
    }
    #undef CONV_STEP
    #undef WROW

    const float* xb = x + (size_t)b * C * L + h * 64;
    float* ob = out + (size_t)b * C * L + h * 64;
    #pragma unroll
    for (int mi = 0; mi < 2; ++mi) {
        #pragma unroll
        for (int r = 0; r < 4; ++r) {
            int co = (2 * wv + mi) * 16 + g * 4 + r;
            float bias = lb[co];
            #pragma unroll
            for (int nt = 0; nt < 2; ++nt) {
                int p_ = half * 32 + nt * 16 + n;
                float v = leaky(acc[mi][nt][r] + bias);
                ob[(size_t)co * L + p_] = v + xb[(size_t)co * L + p_];
            }
        }
    }
}

// ---------------------------------------------------------------------------
extern "C" void kernel_launch(void* const* d_in, const int* in_sizes, int n_in,
                              void* d_out, int out_size, void* d_ws, size_t ws_size,
                              hipStream_t stream) {
    const float* x     = (const float*)d_in[0];
    const float* vw    = (const float*)d_in[1];
    const float* vb    = (const float*)d_in[2];
    const float* qw    = (const float*)d_in[3];
    const float* qb    = (const float*)d_in[4];
    const float* lw1w  = (const float*)d_in[5];
    const float* lw1b  = (const float*)d_in[6];
    const float* lw2w  = (const float*)d_in[7];
    const float* lw2b  = (const float*)d_in[8];
    const float* bi1w  = (const float*)d_in[9];
    const float* bi1b  = (const float*)d_in[10];
    const float* bi2w  = (const float*)d_in[11];
    const float* bi2b  = (const float*)d_in[12];
    const float* lw    = (const float*)d_in[13];
    const float* lb    = (const float*)d_in[14];
    float* out = (float*)d_out;

    char* ws = (char*)d_ws;
    ushort_t* x2a  = (ushort_t*)ws;                      // 2 MB  (attnb alias)
    ushort_t* x1g  = (ushort_t*)(ws + 2097152);          // 2 MB  (W3 alias, post-attn)
    ushort_t* Opb  = (ushort_t*)(ws + 4194304);          // 8 MB  (RS=4 partials)
    ushort_t* WQV  = (ushort_t*)(ws + 4194304);          // 80 KB, dead before k_attn
    float* biasv = (float*)(ws + 4194304 + 81920);       // 1280 B, dead before k_attn
    float* weiA  = (float*)(ws + 12582912);              // 32 KB each
    float* biiA  = weiA + BB * L;
    float* scA   = biiA + BB * L;
    float* Mp    = scA + BB * L;                         // RS*BB*L
    float* Zp    = Mp + RS * BB * L;                     // RS*BB*L
    float* cpart = Zp + RS * BB * L;                     // 64 KB
    float* cbv   = cpart + 128 * 128;                    // BB*128
    ushort_t* W3 = x1g;                                  // 288 KB (after k_attn)
    ushort_t* attnb = x2a;

    hipLaunchKernelGGL(k_wcomp, dim3(20), dim3(256), 0, stream,
                       vw, vb, qw, qb, lw1w, lw1b, bi1w, bi1b, WQV, biasv);

    hipLaunchKernelGGL(k_proj2, dim3(128, 2), dim3(256), 0, stream,
                       x, WQV, biasv, lw2w, lw2b, bi2w, bi2b,
                       x2a, x1g, weiA, biiA, scA, cpart);

    hipLaunchKernelGGL(k_cb, dim3(BB), dim3(128), 0, stream, cpart, cbv);

    hipLaunchKernelGGL(k_attn, dim3(BB * 64 * RS), dim3(256), 0, stream,
                       x2a, x1g, scA, weiA, biiA, cbv, Opb, Mp, Zp);

    hipLaunchKernelGGL(k_mergewrep, dim3(1096), dim3(256), 0, stream,
                       Opb, Mp, Zp, attnb, lw, W3);

    hipLaunchKernelGGL(k_conv, dim3(64, 2, BB), dim3(256), 0, stream,
                       attnb, x, W3, lb, out);
}